// Round 1
// baseline (1068.384 us; speedup 1.0000x reference)
//
#include <hip/hip_runtime.h>

// SortPool2D: x (16,224,224,256) fp32 NHWC -> out (16,112,112,256) fp32.
// For each output (b,h,w,c): sort the 2x2 spatial block {x[b,2h+dh,2w+dw,c]}
// ascending, dot with softmax(pool_weights). K_TOP=4 => all 4 sorted values.
//
// One thread per float4 of output. 64 float4 per output pixel => one wave64
// covers exactly one pixel's channels: every global load/store is a fully
// coalesced 64x16B = 1KB transaction. Memory-bound: ~1.03 GB total traffic.

#define HW_IN   224
#define HW_OUT  112
#define C4      64            // 256 channels / 4 per float4
#define ROW4    (HW_IN * C4)  // float4 stride between input rows = 14336

__device__ __forceinline__ void cswap(float& a, float& b) {
    float lo = fminf(a, b);
    float hi = fmaxf(a, b);
    a = lo; b = hi;
}

__device__ __forceinline__ float sort4_dot(float v0, float v1, float v2, float v3,
                                           float w0, float w1, float w2, float w3) {
    // 5-comparator sorting network for 4 elements (ascending)
    cswap(v0, v1);
    cswap(v2, v3);
    cswap(v0, v2);
    cswap(v1, v3);
    cswap(v1, v2);
    return fmaf(w0, v0, fmaf(w1, v1, fmaf(w2, v2, w3 * v3)));
}

__global__ __launch_bounds__(256) void SortPool2D_kernel(
    const float4* __restrict__ x,
    const float*  __restrict__ pw,
    float4*       __restrict__ out,
    int n4)
{
    int idx = blockIdx.x * blockDim.x + threadIdx.x;
    if (idx >= n4) return;

    // softmax over the 4 pool weights (uniform across threads; L1-hit loads)
    float p0 = pw[0], p1 = pw[1], p2 = pw[2], p3 = pw[3];
    float m  = fmaxf(fmaxf(p0, p1), fmaxf(p2, p3));
    float e0 = expf(p0 - m), e1 = expf(p1 - m), e2 = expf(p2 - m), e3 = expf(p3 - m);
    float inv = 1.0f / (e0 + e1 + e2 + e3);
    e0 *= inv; e1 *= inv; e2 *= inv; e3 *= inv;

    // decompose output float4 index: idx = ((b*112 + h)*112 + w)*64 + c4
    int c  = idx & (C4 - 1);
    int t  = idx >> 6;
    int w  = t % HW_OUT;
    t      = t / HW_OUT;
    int h  = t % HW_OUT;
    int b  = t / HW_OUT;

    int base = ((b * HW_IN + 2 * h) * HW_IN + 2 * w) * C4 + c;  // < 2^31, int ok

    float4 a00 = x[base];
    float4 a01 = x[base + C4];
    float4 a10 = x[base + ROW4];
    float4 a11 = x[base + ROW4 + C4];

    float4 r;
    r.x = sort4_dot(a00.x, a01.x, a10.x, a11.x, e0, e1, e2, e3);
    r.y = sort4_dot(a00.y, a01.y, a10.y, a11.y, e0, e1, e2, e3);
    r.z = sort4_dot(a00.z, a01.z, a10.z, a11.z, e0, e1, e2, e3);
    r.w = sort4_dot(a00.w, a01.w, a10.w, a11.w, e0, e1, e2, e3);

    out[idx] = r;
}

extern "C" void kernel_launch(void* const* d_in, const int* in_sizes, int n_in,
                              void* d_out, int out_size, void* d_ws, size_t ws_size,
                              hipStream_t stream) {
    const float4* x  = (const float4*)d_in[0];
    const float*  pw = (const float*)d_in[1];
    float4*       out = (float4*)d_out;

    int n4 = out_size / 4;                    // 16*112*112*64 = 12,845,056
    int block = 256;
    int grid = (n4 + block - 1) / block;      // 50,176
    SortPool2D_kernel<<<grid, block, 0, stream>>>(x, pw, out, n4);
}